// Round 1
// baseline (456.002 us; speedup 1.0000x reference)
//
#include <hip/hip_runtime.h>
#include <math.h>

#define HH   4096
#define NKV  8
#define GRP  4
#define HD   128
#define FFN  11008
#define NB   16
#define SC   4096
#define SCALE 0.08838834764831845f   // 1/sqrt(128)
#define GTH  512                      // gemv h-tile
#define SCH  512                      // attention chunk

// ---------------------------------------------------------------- RMSNorm
__global__ void rmsnorm_k(const float* __restrict__ x, const float* __restrict__ w,
                          float* __restrict__ y) {
  int b = blockIdx.x;
  const float* xb = x + (size_t)b * HH;
  float* yb = y + (size_t)b * HH;
  int t = threadIdx.x;                       // 256 threads
  int lane = t & 63, wave = t >> 6;
  float4 v[4];
  float ss = 0.f;
#pragma unroll
  for (int i = 0; i < 4; ++i) {
    v[i] = *(const float4*)(xb + 4 * (t + 256 * i));
    ss += v[i].x * v[i].x + v[i].y * v[i].y + v[i].z * v[i].z + v[i].w * v[i].w;
  }
#pragma unroll
  for (int m = 1; m < 64; m <<= 1) ss += __shfl_xor(ss, m);
  __shared__ float red[4];
  if (lane == 0) red[wave] = ss;
  __syncthreads();
  float tot = red[0] + red[1] + red[2] + red[3];
  float rs = rsqrtf(tot * (1.0f / HH) + 1e-5f);
#pragma unroll
  for (int i = 0; i < 4; ++i) {
    int h = 4 * (t + 256 * i);
    float4 wv = *(const float4*)(w + h);
    float4 o;
    o.x = v[i].x * rs * wv.x;
    o.y = v[i].y * rs * wv.y;
    o.z = v[i].z * rs * wv.z;
    o.w = v[i].w * rs * wv.w;
    *(float4*)(yb + h) = o;
  }
}

// ---------------------------------------------------------------- GEMV
// MODE 0: qkv fused   (W0=Wq,W1=Wk,W2=Wv; x0=xn1; y0=q,y1=k_new,y2=v_new) O=6144,H=4096
// MODE 1: Wo + res    (W0=Wo; x0=attn; res=hidden; y0=h2)                 O=4096,H=4096
// MODE 2: Wg|Wu fused (W0=Wg,W1=Wu; x0=xn2; y0=g,y1=u)                    O=22016,H=4096
// MODE 3: Wd + res    (W0=Wd; x0=g,x1=u (silu(g)*u on stage); res=h2)     O=4096,H=11008
template <int MODE>
__global__ __launch_bounds__(256, 2) void gemv_k(
    const float* __restrict__ W0, const float* __restrict__ W1,
    const float* __restrict__ W2, const float* __restrict__ x0,
    const float* __restrict__ x1, const float* __restrict__ res,
    float* __restrict__ y0, float* __restrict__ y1, float* __restrict__ y2,
    int O, int H) {
  __shared__ float xs[NB * GTH];          // 32 KB
  __shared__ float red[4][NB][68];        // padded: conflict-free transpose reduce
  int t = threadIdx.x, lane = t & 63, wave = t >> 6;
  int obase = blockIdx.x * 16 + wave * 4;

  const float* wrow[4];
#pragma unroll
  for (int oi = 0; oi < 4; ++oi) {
    int o = obase + oi;
    const float* wp;
    if (MODE == 0) {
      if (o < 4096) wp = W0 + (size_t)o * H;
      else if (o < 5120) wp = W1 + (size_t)(o - 4096) * H;
      else wp = W2 + (size_t)(o - 5120) * H;
    } else if (MODE == 2) {
      wp = (o < FFN) ? W0 + (size_t)o * H : W1 + (size_t)(o - FFN) * H;
    } else {
      wp = W0 + (size_t)o * H;
    }
    wrow[oi] = wp;
  }

  float acc[4][16];
#pragma unroll
  for (int oi = 0; oi < 4; ++oi)
#pragma unroll
    for (int b = 0; b < 16; ++b) acc[oi][b] = 0.f;

  int ntiles = (H + GTH - 1) / GTH;
  for (int tt = 0; tt < ntiles; ++tt) {
    int hb = tt * GTH;
    int len = H - hb; if (len > GTH) len = GTH;     // 512 or 256 (both pow2*4)
    int nf4 = len >> 2;
    int sh = (len == GTH) ? 7 : 6;                  // log2(nf4)
    for (int j = t; j < NB * nf4; j += 256) {
      int b = j >> sh;
      int hh = (j & (nf4 - 1)) << 2;
      float4 vv;
      if (MODE == 3) {
        float4 g4 = *(const float4*)(x0 + (size_t)b * H + hb + hh);
        float4 u4 = *(const float4*)(x1 + (size_t)b * H + hb + hh);
        vv.x = g4.x / (1.f + __expf(-g4.x)) * u4.x;
        vv.y = g4.y / (1.f + __expf(-g4.y)) * u4.y;
        vv.z = g4.z / (1.f + __expf(-g4.z)) * u4.z;
        vv.w = g4.w / (1.f + __expf(-g4.w)) * u4.w;
      } else {
        vv = *(const float4*)(x0 + (size_t)b * H + hb + hh);
      }
      *(float4*)&xs[b * GTH + hh] = vv;
    }
    __syncthreads();
    for (int hs = 0; hs < len; hs += 256) {
      int h = hs + 4 * lane;
      float4 w4[4];
#pragma unroll
      for (int oi = 0; oi < 4; ++oi)
        w4[oi] = *(const float4*)(wrow[oi] + hb + h);
#pragma unroll
      for (int b = 0; b < 16; ++b) {
        float4 xv = *(const float4*)&xs[b * GTH + h];
#pragma unroll
        for (int oi = 0; oi < 4; ++oi)
          acc[oi][b] += w4[oi].x * xv.x + w4[oi].y * xv.y +
                        w4[oi].z * xv.z + w4[oi].w * xv.w;
      }
    }
    __syncthreads();
  }

  // per-wave reduce over lanes (h-slices) via LDS transpose + shfl
#pragma unroll
  for (int oi = 0; oi < 4; ++oi) {
#pragma unroll
    for (int b = 0; b < 16; ++b) red[wave][b][lane] = acc[oi][b];
    asm volatile("s_waitcnt lgkmcnt(0)" ::: "memory");
    int rb = lane & 15, rj = lane >> 4;
    const float* rp = &red[wave][rb][rj * 16];
    float4 a0 = *(const float4*)rp;
    float4 a1 = *(const float4*)(rp + 4);
    float4 a2 = *(const float4*)(rp + 8);
    float4 a3 = *(const float4*)(rp + 12);
    float s = ((a0.x + a0.y) + (a0.z + a0.w)) + ((a1.x + a1.y) + (a1.z + a1.w)) +
              ((a2.x + a2.y) + (a2.z + a2.w)) + ((a3.x + a3.y) + (a3.z + a3.w));
    s += __shfl_xor(s, 16);
    s += __shfl_xor(s, 32);
    if (lane < 16) {
      int b = lane;
      int o = obase + oi;
      if (MODE == 0) {
        if (o < 4096) y0[(size_t)b * 4096 + o] = s;
        else if (o < 5120) y1[(size_t)b * 1024 + (o - 4096)] = s;
        else y2[(size_t)b * 1024 + (o - 5120)] = s;
      } else if (MODE == 2) {
        if (o < FFN) y0[(size_t)b * FFN + o] = s;
        else y1[(size_t)b * FFN + (o - FFN)] = s;
      } else {
        y0[(size_t)b * 4096 + o] = res[(size_t)b * 4096 + o] + s;
      }
    }
  }
}

// ---------------------------------------------------------------- attention: split-S partials
__global__ __launch_bounds__(256, 2) void attn_part_k(
    const float* __restrict__ q, const float* __restrict__ kc,
    const float* __restrict__ vc, float* __restrict__ pm,
    float* __restrict__ pl, float* __restrict__ pacc) {
  int c = blockIdx.x, kv = blockIdx.y, b = blockIdx.z;
  int t = threadIdx.x, lane = t & 63, wave = t >> 6;
  int ds = lane & 15, ss = lane >> 4;    // 16 lanes/position, 4 positions/wave-step
  __shared__ float sc[GRP][SCH];         // 8 KB scores
  __shared__ float mg[GRP];
  __shared__ float accw[4][GRP][HD];     // 8 KB per-wave PV partials
  __shared__ float lw[4][GRP];

  float4 qv[GRP][2];
  const float* qb = q + (size_t)b * HH + (size_t)kv * GRP * HD;
#pragma unroll
  for (int g = 0; g < GRP; ++g) {
    qv[g][0] = *(const float4*)(qb + g * HD + 8 * ds);
    qv[g][1] = *(const float4*)(qb + g * HD + 8 * ds + 4);
  }
  const size_t kvoff = ((size_t)b * NKV + kv) * (size_t)SC * HD;
  const float* kb = kc + kvoff;

  // pass 1: scores
  for (int st = 0; st < SCH / 16; ++st) {
    int sl = st * 16 + wave * 4 + ss;
    const float* kr = kb + (size_t)(c * SCH + sl) * HD + 8 * ds;
    float4 k0 = *(const float4*)kr;
    float4 k1 = *(const float4*)(kr + 4);
    float d[GRP];
#pragma unroll
    for (int g = 0; g < GRP; ++g)
      d[g] = qv[g][0].x * k0.x + qv[g][0].y * k0.y + qv[g][0].z * k0.z + qv[g][0].w * k0.w +
             qv[g][1].x * k1.x + qv[g][1].y * k1.y + qv[g][1].z * k1.z + qv[g][1].w * k1.w;
#pragma unroll
    for (int m = 1; m < 16; m <<= 1)
#pragma unroll
      for (int g = 0; g < GRP; ++g) d[g] += __shfl_xor(d[g], m);
    if (ds < GRP) sc[ds][sl] = d[ds] * SCALE;
  }
  __syncthreads();

  // per-group max over chunk (wave g handles group g)
  {
    int g = wave;
    float m = -1e30f;
    for (int i = lane; i < SCH; i += 64) m = fmaxf(m, sc[g][i]);
#pragma unroll
    for (int mm = 1; mm < 64; mm <<= 1) m = fmaxf(m, __shfl_xor(m, mm));
    if (lane == 0) mg[g] = m;
  }
  __syncthreads();
  float mreg[GRP];
#pragma unroll
  for (int g = 0; g < GRP; ++g) mreg[g] = mg[g];

  // pass 2: exp + PV
  float acc[GRP][8];
  float lacc[GRP];
#pragma unroll
  for (int g = 0; g < GRP; ++g) {
    lacc[g] = 0.f;
#pragma unroll
    for (int j = 0; j < 8; ++j) acc[g][j] = 0.f;
  }
  const float* vb = vc + kvoff;
  for (int st = 0; st < SCH / 16; ++st) {
    int sl = st * 16 + wave * 4 + ss;
    const float* vr = vb + (size_t)(c * SCH + sl) * HD + 8 * ds;
    float4 v0 = *(const float4*)vr;
    float4 v1 = *(const float4*)(vr + 4);
    float p[GRP];
#pragma unroll
    for (int g = 0; g < GRP; ++g) p[g] = __expf(sc[g][sl] - mreg[g]);
    if (ds == 0) {
#pragma unroll
      for (int g = 0; g < GRP; ++g) lacc[g] += p[g];
    }
#pragma unroll
    for (int g = 0; g < GRP; ++g) {
      acc[g][0] += p[g] * v0.x; acc[g][1] += p[g] * v0.y;
      acc[g][2] += p[g] * v0.z; acc[g][3] += p[g] * v0.w;
      acc[g][4] += p[g] * v1.x; acc[g][5] += p[g] * v1.y;
      acc[g][6] += p[g] * v1.z; acc[g][7] += p[g] * v1.w;
    }
  }
  // reduce over the 4 position-subgroups
#pragma unroll
  for (int m = 16; m < 64; m <<= 1) {
#pragma unroll
    for (int g = 0; g < GRP; ++g) {
#pragma unroll
      for (int j = 0; j < 8; ++j) acc[g][j] += __shfl_xor(acc[g][j], m);
      lacc[g] += __shfl_xor(lacc[g], m);
    }
  }
  if (ss == 0) {
#pragma unroll
    for (int g = 0; g < GRP; ++g) {
      float4 lo = make_float4(acc[g][0], acc[g][1], acc[g][2], acc[g][3]);
      float4 hi = make_float4(acc[g][4], acc[g][5], acc[g][6], acc[g][7]);
      *(float4*)&accw[wave][g][8 * ds] = lo;
      *(float4*)&accw[wave][g][8 * ds + 4] = hi;
    }
    if (ds == 0) {
#pragma unroll
      for (int g = 0; g < GRP; ++g) lw[wave][g] = lacc[g];
    }
  }
  __syncthreads();

  size_t pbase = (((size_t)(b * NKV + kv)) * 8 + c) * GRP;  // 8 chunks
  for (int idx = t; idx < GRP * HD; idx += 256) {
    int g = idx >> 7, dd = idx & 127;
    float o = accw[0][g][dd] + accw[1][g][dd] + accw[2][g][dd] + accw[3][g][dd];
    pacc[(pbase + g) * HD + dd] = o;
  }
  if (t < GRP) {
    pm[pbase + t] = mg[t];
    pl[pbase + t] = lw[0][t] + lw[1][t] + lw[2][t] + lw[3][t];
  }
}

// ---------------------------------------------------------------- attention: reduce + new token
__global__ void attn_red_k(const float* __restrict__ q, const float* __restrict__ knew,
                           const float* __restrict__ vnew, const float* __restrict__ pm,
                           const float* __restrict__ pl, const float* __restrict__ pacc,
                           float* __restrict__ attn) {
  int bi = blockIdx.x;                 // 128 = 16b * 8kv
  int b = bi >> 3, kv = bi & 7;
  int t = threadIdx.x, lane = t & 63, wave = t >> 6;
  __shared__ float sn[GRP];
  {
    int g = wave;                      // 4 waves, one per group
    float2 qv = *(const float2*)(q + (size_t)b * HH + (size_t)(kv * GRP + g) * HD + 2 * lane);
    float2 k2 = *(const float2*)(knew + (size_t)b * (NKV * HD) + kv * HD + 2 * lane);
    float d = qv.x * k2.x + qv.y * k2.y;
#pragma unroll
    for (int m = 1; m < 64; m <<= 1) d += __shfl_xor(d, m);
    if (lane == 0) sn[g] = d * SCALE;
  }
  __syncthreads();
  size_t base = ((size_t)(b * NKV + kv)) * 8;
  for (int idx = t; idx < GRP * HD; idx += 256) {
    int g = idx >> 7, dd = idx & 127;
    float snv = sn[g];
    float M = snv;
    float pmv[8];
#pragma unroll
    for (int cc = 0; cc < 8; ++cc) {
      pmv[cc] = pm[(base + cc) * GRP + g];
      M = fmaxf(M, pmv[cc]);
    }
    float en = __expf(snv - M);
    float L = en;
    float o = en * vnew[(size_t)b * (NKV * HD) + kv * HD + dd];
#pragma unroll
    for (int cc = 0; cc < 8; ++cc) {
      float f = __expf(pmv[cc] - M);
      L += f * pl[(base + cc) * GRP + g];
      o += f * pacc[((base + cc) * GRP + g) * HD + dd];
    }
    attn[(size_t)b * HH + (size_t)(kv * GRP + g) * HD + dd] = o / L;
  }
}

// ---------------------------------------------------------------- launch
extern "C" void kernel_launch(void* const* d_in, const int* in_sizes, int n_in,
                              void* d_out, int out_size, void* d_ws, size_t ws_size,
                              hipStream_t stream) {
  const float* hidden = (const float*)d_in[0];
  const float* kc = (const float*)d_in[1];
  const float* vc = (const float*)d_in[2];
  const float* Wq = (const float*)d_in[3];
  const float* Wk = (const float*)d_in[4];
  const float* Wv = (const float*)d_in[5];
  const float* Wo = (const float*)d_in[6];
  const float* Wg = (const float*)d_in[7];
  const float* Wu = (const float*)d_in[8];
  const float* Wd = (const float*)d_in[9];
  const float* ln1 = (const float*)d_in[10];
  const float* ln2 = (const float*)d_in[11];
  float* out = (float*)d_out;

  float* ws = (float*)d_ws;
  float* xn1 = ws;                 // 65536
  float* qb = xn1 + 65536;         // 65536
  float* kn = qb + 65536;          // 16384
  float* vn = kn + 16384;          // 16384
  float* attn = vn + 16384;        // 65536
  float* h2 = attn + 65536;        // 65536
  float* xn2 = h2 + 65536;         // 65536
  float* gb = xn2 + 65536;         // 176128
  float* ub = gb + 176128;         // 176128
  float* pm = ub + 176128;         // 4096
  float* pl = pm + 4096;           // 4096
  float* pacc = pl + 4096;         // 524288

  rmsnorm_k<<<16, 256, 0, stream>>>(hidden, ln1, xn1);
  gemv_k<0><<<384, 256, 0, stream>>>(Wq, Wk, Wv, xn1, nullptr, nullptr,
                                     qb, kn, vn, 6144, 4096);
  attn_part_k<<<dim3(8, 8, 16), 256, 0, stream>>>(qb, kc, vc, pm, pl, pacc);
  attn_red_k<<<128, 256, 0, stream>>>(qb, kn, vn, pm, pl, pacc, attn);
  gemv_k<1><<<256, 256, 0, stream>>>(Wo, nullptr, nullptr, attn, nullptr, hidden,
                                     h2, nullptr, nullptr, 4096, 4096);
  rmsnorm_k<<<16, 256, 0, stream>>>(h2, ln2, xn2);
  gemv_k<2><<<1376, 256, 0, stream>>>(Wg, Wu, nullptr, xn2, nullptr, nullptr,
                                      gb, ub, nullptr, 22016, 4096);
  gemv_k<3><<<256, 256, 0, stream>>>(Wd, nullptr, nullptr, gb, ub, h2,
                                     out, nullptr, nullptr, 4096, 11008);
}

// Round 2
// 295.188 us; speedup vs baseline: 1.5448x; 1.5448x over previous
//
#include <hip/hip_runtime.h>
#include <math.h>

#define HH   4096
#define NKV  8
#define GRP  4
#define HD   128
#define FFN  11008
#define NB   16
#define SC   4096
#define SCALE 0.08838834764831845f   // 1/sqrt(128)
#define GTH  1024                     // gemv h-tile (4 steps per barrier)
#define SCH  512                      // attention chunk

typedef float f4v __attribute__((ext_vector_type(4)));

__device__ __forceinline__ f4v ntload4(const float* p) {
  return __builtin_nontemporal_load((const f4v*)p);
}
__device__ __forceinline__ float dot4(f4v a, f4v b) {
  return a[0] * b[0] + a[1] * b[1] + a[2] * b[2] + a[3] * b[3];
}

// ---------------------------------------------------------------- RMSNorm
__global__ void rmsnorm_k(const float* __restrict__ x, const float* __restrict__ w,
                          float* __restrict__ y) {
  int b = blockIdx.x;
  const float* xb = x + (size_t)b * HH;
  float* yb = y + (size_t)b * HH;
  int t = threadIdx.x;                       // 256 threads
  int lane = t & 63, wave = t >> 6;
  f4v v[4];
  float ss = 0.f;
#pragma unroll
  for (int i = 0; i < 4; ++i) {
    v[i] = *(const f4v*)(xb + 4 * (t + 256 * i));
    ss += dot4(v[i], v[i]);
  }
#pragma unroll
  for (int m = 1; m < 64; m <<= 1) ss += __shfl_xor(ss, m);
  __shared__ float red[4];
  if (lane == 0) red[wave] = ss;
  __syncthreads();
  float tot = red[0] + red[1] + red[2] + red[3];
  float rs = rsqrtf(tot * (1.0f / HH) + 1e-5f);
#pragma unroll
  for (int i = 0; i < 4; ++i) {
    int h = 4 * (t + 256 * i);
    f4v wv = *(const f4v*)(w + h);
    f4v o = v[i] * rs * wv;
    *(f4v*)(yb + h) = o;
  }
}

// ---------------------------------------------------------------- GEMV
// MODE 0 (WOUT=2): qkv fused   W0=Wq,W1=Wk,W2=Wv; x0=xn1; y0=q,y1=k_new,y2=v_new
// MODE 1 (WOUT=2): Wo + res    W0=Wo; x0=attn; res=hidden; y0=h2
// MODE 2 (WOUT=4): Wg/Wu pair  W0=Wg,W1=Wu; x0=xn2; y0 = gu = silu(g)*u
// MODE 3 (WOUT=2): Wd + res    W0=Wd; x0=gu; res=h2; y0=out
template <int MODE, int WOUT>
__global__ __launch_bounds__(256, 2) void gemv_k(
    const float* __restrict__ W0, const float* __restrict__ W1,
    const float* __restrict__ W2, const float* __restrict__ x0,
    const float* __restrict__ res,
    float* __restrict__ y0, float* __restrict__ y1, float* __restrict__ y2,
    int H) {
  __shared__ float xs[NB * GTH];          // 64 KB; reduce scratch aliased in
  int t = threadIdx.x, lane = t & 63, wave = t >> 6;

  const float* wrow[WOUT];
  int obase;
  if (MODE == 2) {
    int pbase = blockIdx.x * 8 + wave * 2;     // pair index into FFN
    obase = pbase;
    wrow[0] = W0 + (size_t)pbase * H;          // g row p
    wrow[1] = W1 + (size_t)pbase * H;          // u row p
    wrow[2] = W0 + (size_t)(pbase + 1) * H;    // g row p+1
    wrow[3] = W1 + (size_t)(pbase + 1) * H;    // u row p+1
  } else {
    obase = blockIdx.x * (4 * WOUT) + wave * WOUT;
#pragma unroll
    for (int oi = 0; oi < WOUT; ++oi) {
      int o = obase + oi;
      const float* wp;
      if (MODE == 0) {
        if (o < 4096) wp = W0 + (size_t)o * H;
        else if (o < 5120) wp = W1 + (size_t)(o - 4096) * H;
        else wp = W2 + (size_t)(o - 5120) * H;
      } else {
        wp = W0 + (size_t)o * H;
      }
      wrow[oi] = wp;
    }
  }

  float acc[WOUT][NB];
#pragma unroll
  for (int oi = 0; oi < WOUT; ++oi)
#pragma unroll
    for (int b = 0; b < NB; ++b) acc[oi][b] = 0.f;

  for (int hb = 0; hb < H; hb += GTH) {
    int len = H - hb; if (len > GTH) len = GTH;
    // stage x tile: thread t covers hh = 4t (+1024) for every batch
#pragma unroll
    for (int b = 0; b < NB; ++b) {
      for (int hh = 4 * t; hh < len; hh += 1024) {
        *(f4v*)&xs[b * GTH + hh] = *(const f4v*)(x0 + (size_t)b * H + hb + hh);
      }
    }
    __syncthreads();
    for (int hs = 0; hs < len; hs += 256) {
      int h = hs + 4 * lane;
      f4v w4[WOUT];
#pragma unroll
      for (int oi = 0; oi < WOUT; ++oi) w4[oi] = ntload4(wrow[oi] + hb + h);
#pragma unroll
      for (int b = 0; b < NB; ++b) {
        f4v xv = *(const f4v*)&xs[b * GTH + h];
#pragma unroll
        for (int oi = 0; oi < WOUT; ++oi) acc[oi][b] += dot4(w4[oi], xv);
      }
    }
    __syncthreads();
  }

  // per-wave reduce over lanes via LDS transpose (aliased into xs) + shfl
#define RED(w_, b_, l_) xs[(((w_) * NB + (b_)) * 68) + (l_)]
  float sarr[WOUT];
#pragma unroll
  for (int oi = 0; oi < WOUT; ++oi) {
    asm volatile("s_waitcnt lgkmcnt(0)" ::: "memory");
#pragma unroll
    for (int b = 0; b < NB; ++b) RED(wave, b, lane) = acc[oi][b];
    asm volatile("s_waitcnt lgkmcnt(0)" ::: "memory");
    int rb = lane & 15, rj = lane >> 4;
    const float* rp = &RED(wave, rb, rj * 16);
    f4v a0 = *(const f4v*)rp;
    f4v a1 = *(const f4v*)(rp + 4);
    f4v a2 = *(const f4v*)(rp + 8);
    f4v a3 = *(const f4v*)(rp + 12);
    float s = ((a0[0] + a0[1]) + (a0[2] + a0[3])) + ((a1[0] + a1[1]) + (a1[2] + a1[3])) +
              ((a2[0] + a2[1]) + (a2[2] + a2[3])) + ((a3[0] + a3[1]) + (a3[2] + a3[3]));
    s += __shfl_xor(s, 16);
    s += __shfl_xor(s, 32);
    sarr[oi] = s;
  }
  if (lane < 16) {
    int b = lane;
    if (MODE == 2) {
#pragma unroll
      for (int p = 0; p < 2; ++p) {
        float g = sarr[2 * p], u = sarr[2 * p + 1];
        y0[(size_t)b * FFN + (obase + p)] = g / (1.f + __expf(-g)) * u;
      }
    } else {
#pragma unroll
      for (int oi = 0; oi < WOUT; ++oi) {
        float s = sarr[oi];
        int o = obase + oi;
        if (MODE == 0) {
          if (o < 4096) y0[(size_t)b * 4096 + o] = s;
          else if (o < 5120) y1[(size_t)b * 1024 + (o - 4096)] = s;
          else y2[(size_t)b * 1024 + (o - 5120)] = s;
        } else {
          y0[(size_t)b * 4096 + o] = res[(size_t)b * 4096 + o] + s;
        }
      }
    }
  }
#undef RED
}

// ---------------------------------------------------------------- attention: split-S partials
__global__ __launch_bounds__(256, 4) void attn_part_k(
    const float* __restrict__ q, const float* __restrict__ kc,
    const float* __restrict__ vc, float* __restrict__ pm,
    float* __restrict__ pl, float* __restrict__ pacc) {
  int c = blockIdx.x, kv = blockIdx.y, b = blockIdx.z;
  int t = threadIdx.x, lane = t & 63, wave = t >> 6;
  int ds = lane & 15, ss = lane >> 4;    // 16 lanes/position, 4 positions/wave-step
  __shared__ float sc[GRP][SCH];         // 8 KB scores
  __shared__ float mg[GRP];
  __shared__ float accw[4][GRP][HD];     // 8 KB per-wave PV partials
  __shared__ float lw[4][GRP];

  f4v qv[GRP][2];
  const float* qb = q + (size_t)b * HH + (size_t)kv * GRP * HD;
#pragma unroll
  for (int g = 0; g < GRP; ++g) {
    qv[g][0] = *(const f4v*)(qb + g * HD + 8 * ds);
    qv[g][1] = *(const f4v*)(qb + g * HD + 8 * ds + 4);
  }
  const size_t kvoff = ((size_t)b * NKV + kv) * (size_t)SC * HD;
  const float* kb = kc + kvoff;

  // pass 1: scores
  for (int st = 0; st < SCH / 16; ++st) {
    int sl = st * 16 + wave * 4 + ss;
    const float* kr = kb + (size_t)(c * SCH + sl) * HD + 8 * ds;
    f4v k0 = ntload4(kr);
    f4v k1 = ntload4(kr + 4);
    float d[GRP];
#pragma unroll
    for (int g = 0; g < GRP; ++g)
      d[g] = dot4(qv[g][0], k0) + dot4(qv[g][1], k1);
#pragma unroll
    for (int m = 1; m < 16; m <<= 1)
#pragma unroll
      for (int g = 0; g < GRP; ++g) d[g] += __shfl_xor(d[g], m);
    if (ds < GRP) sc[ds][sl] = d[ds] * SCALE;
  }
  __syncthreads();

  // per-group max over chunk (wave g handles group g)
  {
    int g = wave;
    float m = -1e30f;
    for (int i = lane; i < SCH; i += 64) m = fmaxf(m, sc[g][i]);
#pragma unroll
    for (int mm = 1; mm < 64; mm <<= 1) m = fmaxf(m, __shfl_xor(m, mm));
    if (lane == 0) mg[g] = m;
  }
  __syncthreads();
  float mreg[GRP];
#pragma unroll
  for (int g = 0; g < GRP; ++g) mreg[g] = mg[g];

  // pass 2: exp + PV
  float acc[GRP][8];
  float lacc[GRP];
#pragma unroll
  for (int g = 0; g < GRP; ++g) {
    lacc[g] = 0.f;
#pragma unroll
    for (int j = 0; j < 8; ++j) acc[g][j] = 0.f;
  }
  const float* vb = vc + kvoff;
  for (int st = 0; st < SCH / 16; ++st) {
    int sl = st * 16 + wave * 4 + ss;
    const float* vr = vb + (size_t)(c * SCH + sl) * HD + 8 * ds;
    f4v v0 = ntload4(vr);
    f4v v1 = ntload4(vr + 4);
    float p[GRP];
#pragma unroll
    for (int g = 0; g < GRP; ++g) p[g] = __expf(sc[g][sl] - mreg[g]);
    if (ds == 0) {
#pragma unroll
      for (int g = 0; g < GRP; ++g) lacc[g] += p[g];
    }
#pragma unroll
    for (int g = 0; g < GRP; ++g) {
#pragma unroll
      for (int j = 0; j < 4; ++j) {
        acc[g][j] += p[g] * v0[j];
        acc[g][4 + j] += p[g] * v1[j];
      }
    }
  }
  // reduce over the 4 position-subgroups
#pragma unroll
  for (int m = 16; m < 64; m <<= 1) {
#pragma unroll
    for (int g = 0; g < GRP; ++g) {
#pragma unroll
      for (int j = 0; j < 8; ++j) acc[g][j] += __shfl_xor(acc[g][j], m);
      lacc[g] += __shfl_xor(lacc[g], m);
    }
  }
  if (ss == 0) {
#pragma unroll
    for (int g = 0; g < GRP; ++g) {
#pragma unroll
      for (int j = 0; j < 4; ++j) {
        accw[wave][g][8 * ds + j] = acc[g][j];
        accw[wave][g][8 * ds + 4 + j] = acc[g][4 + j];
      }
    }
    if (ds == 0) {
#pragma unroll
      for (int g = 0; g < GRP; ++g) lw[wave][g] = lacc[g];
    }
  }
  __syncthreads();

  size_t pbase = (((size_t)(b * NKV + kv)) * 8 + c) * GRP;  // 8 chunks
  for (int idx = t; idx < GRP * HD; idx += 256) {
    int g = idx >> 7, dd = idx & 127;
    float o = accw[0][g][dd] + accw[1][g][dd] + accw[2][g][dd] + accw[3][g][dd];
    pacc[(pbase + g) * HD + dd] = o;
  }
  if (t < GRP) {
    pm[pbase + t] = mg[t];
    pl[pbase + t] = lw[0][t] + lw[1][t] + lw[2][t] + lw[3][t];
  }
}

// ---------------------------------------------------------------- attention: reduce + new token
__global__ void attn_red_k(const float* __restrict__ q, const float* __restrict__ knew,
                           const float* __restrict__ vnew, const float* __restrict__ pm,
                           const float* __restrict__ pl, const float* __restrict__ pacc,
                           float* __restrict__ attn) {
  int bi = blockIdx.x;                 // 128 = 16b * 8kv
  int b = bi >> 3, kv = bi & 7;
  int t = threadIdx.x, lane = t & 63, wave = t >> 6;
  __shared__ float sn[GRP];
  {
    int g = wave;                      // 4 waves, one per group
    float2 qv = *(const float2*)(q + (size_t)b * HH + (size_t)(kv * GRP + g) * HD + 2 * lane);
    float2 k2 = *(const float2*)(knew + (size_t)b * (NKV * HD) + kv * HD + 2 * lane);
    float d = qv.x * k2.x + qv.y * k2.y;
#pragma unroll
    for (int m = 1; m < 64; m <<= 1) d += __shfl_xor(d, m);
    if (lane == 0) sn[g] = d * SCALE;
  }
  __syncthreads();
  size_t base = ((size_t)(b * NKV + kv)) * 8;
  for (int idx = t; idx < GRP * HD; idx += 256) {
    int g = idx >> 7, dd = idx & 127;
    float snv = sn[g];
    float M = snv;
    float pmv[8];
#pragma unroll
    for (int cc = 0; cc < 8; ++cc) {
      pmv[cc] = pm[(base + cc) * GRP + g];
      M = fmaxf(M, pmv[cc]);
    }
    float en = __expf(snv - M);
    float L = en;
    float o = en * vnew[(size_t)b * (NKV * HD) + kv * HD + dd];
#pragma unroll
    for (int cc = 0; cc < 8; ++cc) {
      float f = __expf(pmv[cc] - M);
      L += f * pl[(base + cc) * GRP + g];
      o += f * pacc[((base + cc) * GRP + g) * HD + dd];
    }
    attn[(size_t)b * HH + (size_t)(kv * GRP + g) * HD + dd] = o / L;
  }
}

// ---------------------------------------------------------------- launch
extern "C" void kernel_launch(void* const* d_in, const int* in_sizes, int n_in,
                              void* d_out, int out_size, void* d_ws, size_t ws_size,
                              hipStream_t stream) {
  const float* hidden = (const float*)d_in[0];
  const float* kc = (const float*)d_in[1];
  const float* vc = (const float*)d_in[2];
  const float* Wq = (const float*)d_in[3];
  const float* Wk = (const float*)d_in[4];
  const float* Wv = (const float*)d_in[5];
  const float* Wo = (const float*)d_in[6];
  const float* Wg = (const float*)d_in[7];
  const float* Wu = (const float*)d_in[8];
  const float* Wd = (const float*)d_in[9];
  const float* ln1 = (const float*)d_in[10];
  const float* ln2 = (const float*)d_in[11];
  float* out = (float*)d_out;

  float* ws = (float*)d_ws;
  float* xn1 = ws;                 // 65536
  float* qb = xn1 + 65536;         // 65536
  float* kn = qb + 65536;          // 16384
  float* vn = kn + 16384;          // 16384
  float* attn = vn + 16384;        // 65536
  float* h2 = attn + 65536;        // 65536
  float* xn2 = h2 + 65536;         // 65536
  float* gu = xn2 + 65536;         // 176128  (silu(g)*u fused)
  float* pm = gu + 176128;         // 4096
  float* pl = pm + 4096;           // 4096
  float* pacc = pl + 4096;         // 524288

  rmsnorm_k<<<16, 256, 0, stream>>>(hidden, ln1, xn1);
  gemv_k<0, 2><<<768, 256, 0, stream>>>(Wq, Wk, Wv, xn1, nullptr,
                                        qb, kn, vn, 4096);
  attn_part_k<<<dim3(8, 8, 16), 256, 0, stream>>>(qb, kc, vc, pm, pl, pacc);
  attn_red_k<<<128, 256, 0, stream>>>(qb, kn, vn, pm, pl, pacc, attn);
  gemv_k<1, 2><<<512, 256, 0, stream>>>(Wo, nullptr, nullptr, attn, hidden,
                                        h2, nullptr, nullptr, 4096);
  rmsnorm_k<<<16, 256, 0, stream>>>(h2, ln2, xn2);
  gemv_k<2, 4><<<1376, 256, 0, stream>>>(Wg, Wu, nullptr, xn2, nullptr,
                                         gu, nullptr, nullptr, 4096);
  gemv_k<3, 2><<<512, 256, 0, stream>>>(Wd, nullptr, nullptr, gu, h2,
                                        out, nullptr, nullptr, 11008);
}